// Round 11
// baseline (3322.577 us; speedup 1.0000x reference)
//
#include <hip/hip_runtime.h>
#include <hip/hip_bf16.h>
#include <stdint.h>

typedef unsigned long long u64;
typedef unsigned int u32;
typedef unsigned short u16;

#define B_   4
#define C_   64
#define N_   8192
#define M_   2048
#define KNB  16
#define FLT_MAX_ 3.402823466e+38f

__device__ __forceinline__ int clampN(int v) {
    return v < 0 ? 0 : (v > N_ - 1 ? N_ - 1 : v);
}

// ---------------- ws layout (bytes) — TOTAL 524288 ----------------
// idx_ws   : u16[B_*M_]       @ 0       (16384 B)
// nbr_ws   : u16[B_*M_*KNB]   @ 16384   (262144 B)
// pnorm_ws : float[B_*N_]     @ 278528  (131072 B)
// wt_ws    : float[448*64]    @ 409600  (114688 B)
// d_out is FLOAT32 (round-6 discovery): all output stores are f32.

// Pin a float4's lanes into VGPRs: the empty asm's outputs are no longer
// provably equal to the memory they were loaded from, so LLVM cannot
// rematerialize them by re-loading (r10 post-mortem: VGPR_Count=56 because
// px/py/pz were re-fetched from L2 every iteration — ~12 dwordx4/thread/iter).
__device__ __forceinline__ void pin4(float4& v) {
    asm volatile("" : "+v"(v.x), "+v"(v.y), "+v"(v.z), "+v"(v.w));
}

// DPP wave64 max -> returns wave max broadcast (via lane 63 readlane).
__device__ __forceinline__ float wave_fmax_dpp(float v) {
    float t;
    t = __int_as_float(__builtin_amdgcn_update_dpp(0, __float_as_int(v), 0x111, 0xf, 0xf, true)); v = fmaxf(v, t);
    t = __int_as_float(__builtin_amdgcn_update_dpp(0, __float_as_int(v), 0x112, 0xf, 0xf, true)); v = fmaxf(v, t);
    t = __int_as_float(__builtin_amdgcn_update_dpp(0, __float_as_int(v), 0x114, 0xf, 0xf, true)); v = fmaxf(v, t);
    t = __int_as_float(__builtin_amdgcn_update_dpp(0, __float_as_int(v), 0x118, 0xf, 0xf, true)); v = fmaxf(v, t);
    t = __int_as_float(__builtin_amdgcn_update_dpp(0, __float_as_int(v), 0x142, 0xa, 0xf, true)); v = fmaxf(v, t);
    t = __int_as_float(__builtin_amdgcn_update_dpp(0, __float_as_int(v), 0x143, 0xc, 0xf, true)); v = fmaxf(v, t);
    return __int_as_float(__builtin_amdgcn_readlane(__float_as_int(v), 63));
}

// ======================= FPS =======================
// np-exact: d = ((dx*dx + dy*dy) + dz*dz) no contraction; dists=min(dists,d);
// argmax first-index tie-break (strict > keeps first j / ffs first lane /
// ascending wave scan). Coordinates pinned in VGPRs via pin4 (round 11).
#define FPS_STEP(PX, PY, PZ, DD, J)                                          \
    {                                                                        \
        float dx = __fsub_rn((PX), lx);                                      \
        float dy = __fsub_rn((PY), ly);                                      \
        float dz = __fsub_rn((PZ), lz);                                      \
        float d = __fadd_rn(__fadd_rn(__fmul_rn(dx, dx), __fmul_rn(dy, dy)), \
                            __fmul_rn(dz, dz));                              \
        float nd = fminf((DD), d);                                           \
        (DD) = nd;                                                           \
        bool gt = nd > fm;                                                   \
        fm = gt ? nd : fm;                                                   \
        fj = gt ? (J) : fj;                                                  \
        fx = gt ? (PX) : fx;                                                 \
        fy = gt ? (PY) : fy;                                                 \
        fz = gt ? (PZ) : fz;                                                 \
    }

__global__ __launch_bounds__(512, 2) void fps_kernel(const float* __restrict__ xyz,
                                                     u16* __restrict__ idx_ws) {
    const int b = blockIdx.x;
    const int tid = threadIdx.x;
    const int lane = tid & 63;
    const int w = tid >> 6;                 // 8 waves
    const float* xb = xyz + b * 3 * N_;
    const int n0 = tid * 16;

    float4 px[4], py[4], pz[4], dd[4];
#pragma unroll
    for (int j4 = 0; j4 < 4; ++j4) {
        px[j4] = *(const float4*)(xb + n0 + j4 * 4);
        py[j4] = *(const float4*)(xb + N_ + n0 + j4 * 4);
        pz[j4] = *(const float4*)(xb + 2 * N_ + n0 + j4 * 4);
        pin4(px[j4]); pin4(py[j4]); pin4(pz[j4]);
        dd[j4] = make_float4(FLT_MAX_, FLT_MAX_, FLT_MAX_, FLT_MAX_);
    }

    __shared__ float4 red4[2][8];   // {wavemax, x, y, z}
    __shared__ int    redi[2][8];

    int cur = 0;
    float lx = xb[0], ly = xb[N_], lz = xb[2 * N_];
    if (tid == 0) idx_ws[b * M_ + 0] = 0;

    for (int s = 1; s < M_; ++s) {
        float fm = -1.0f, fx = 0.f, fy = 0.f, fz = 0.f;
        int fj = 0;
#pragma unroll
        for (int j4 = 0; j4 < 4; ++j4) {
            FPS_STEP(px[j4].x, py[j4].x, pz[j4].x, dd[j4].x, j4 * 4 + 0);
            FPS_STEP(px[j4].y, py[j4].y, pz[j4].y, dd[j4].y, j4 * 4 + 1);
            FPS_STEP(px[j4].z, py[j4].z, pz[j4].z, dd[j4].z, j4 * 4 + 2);
            FPS_STEP(px[j4].w, py[j4].w, pz[j4].w, dd[j4].w, j4 * 4 + 3);
        }
        float wm = wave_fmax_dpp(fm);       // wave-uniform
        u64 bal = __ballot(fm == wm);       // >=1 bit set
        int winlane = (int)__ffsll(bal) - 1;
        const int par = s & 1;
        if (lane == winlane) {
            red4[par][w] = make_float4(wm, fx, fy, fz);
            redi[par][w] = n0 + fj;
        }
        __syncthreads();
        float4 p0 = red4[par][0];
        float g = p0.x; float nlx = p0.y, nly = p0.z, nlz = p0.w;
        int ncur = redi[par][0];
#pragma unroll
        for (int ww = 1; ww < 8; ++ww) {
            float4 p = red4[par][ww];
            int id = redi[par][ww];
            bool gt = p.x > g;              // strict: keeps first wave on ties
            g = gt ? p.x : g;
            nlx = gt ? p.y : nlx; nly = gt ? p.z : nly; nlz = gt ? p.w : nlz;
            ncur = gt ? id : ncur;
        }
        lx = nlx; ly = nly; lz = nlz; cur = ncur;
        if (tid == 0) idx_ws[b * M_ + s] = (u16)cur;
        // single barrier per iter: next iter writes red4[par^1]
    }
}

// =================== gather: out1 (xyz) / out2 (idx), f32 ===================
__global__ __launch_bounds__(256) void gather_kernel(const float* __restrict__ xyz,
                                                     const u16* __restrict__ idx_ws,
                                                     float* __restrict__ out1,
                                                     float* __restrict__ out2) {
    int gid = blockIdx.x * 256 + threadIdx.x;   // 8192
    int b = gid >> 11, m = gid & 2047;
    int idx = clampN((int)idx_ws[b * M_ + m]);
    out2[b * M_ + m] = (float)idx;
    const float* xyzb = xyz + b * 3 * N_;
#pragma unroll
    for (int d = 0; d < 3; ++d)
        out1[(b * 3 + d) * M_ + m] = xyzb[d * N_ + idx];
}

// =================== point squared norms ===================
__global__ __launch_bounds__(256) void pnorm_kernel(const float* __restrict__ x,
                                                    float* __restrict__ pnorm_ws) {
    int gid = blockIdx.x * 256 + threadIdx.x;   // 32768
    int b = gid >> 13, n = gid & 8191;
    const float* xb = x + b * C_ * N_ + n;
    float acc = 0.f;
#pragma unroll 16
    for (int c = 0; c < C_; ++c) { float v = xb[c * N_]; acc = fmaf(v, v, acc); }
    pnorm_ws[gid] = acc;
}

// =================== weight transpose: W[o][i] -> Wt[i][o] ===================
__global__ __launch_bounds__(256) void wtrans_kernel(const float* __restrict__ W0,
                                                     const float* __restrict__ W1,
                                                     const float* __restrict__ W2,
                                                     float* __restrict__ wt) {
    int e = blockIdx.x * 256 + threadIdx.x;     // 28672
    if (e < 8192) {
        int i = e >> 6, o = e & 63;
        wt[e] = W0[o * 128 + i];
    } else if (e < 16384) {
        int e2 = e - 8192; int i = e2 >> 6, o = e2 & 63;
        wt[8192 + e2] = W1[o * 128 + i];
    } else {
        int e2 = e - 16384; int i = e2 >> 6, o = e2 & 63;
        wt[16384 + e2] = W2[o * 192 + i];
    }
}

// =================== KNN top-17 tiled (drop rank-0 self) ===================
// 32 queries/block x 8 sub-streams; point tiles staged transposed in LDS;
// expanded form d = qn + pn - 2*dot; per-thread sorted top-17; 8-way merge.
__global__ __launch_bounds__(256) void knn_kernel(const float* __restrict__ x,
                                                  const u16* __restrict__ idx_ws,
                                                  const float* __restrict__ pnorm_ws,
                                                  u16* __restrict__ nbr_ws) {
    __shared__ float pt[64 * 68];
    __shared__ float spn[64];
    __shared__ u64 lists[256 * 17];

    const int tid = threadIdx.x;
    const int b = blockIdx.x >> 6;
    const int m0 = (blockIdx.x & 63) * 32;
    const int q = tid & 31, sub = tid >> 5;
    const int m = m0 + q;
    const float* xb = x + b * C_ * N_;
    const int self = clampN((int)idx_ws[b * M_ + m]);

    float4 qv[16];
#pragma unroll
    for (int c4 = 0; c4 < 16; ++c4) {
        qv[c4].x = xb[(c4 * 4 + 0) * N_ + self];
        qv[c4].y = xb[(c4 * 4 + 1) * N_ + self];
        qv[c4].z = xb[(c4 * 4 + 2) * N_ + self];
        qv[c4].w = xb[(c4 * 4 + 3) * N_ + self];
    }
    const float qn = pnorm_ws[b * N_ + self];

    u64* L = lists + tid * 17;
#pragma unroll
    for (int j = 0; j < 17; ++j) L[j] = ~0ULL;
    u64 worst = ~0ULL;

    for (int t = 0; t < N_ / 64; ++t) {
        const int nb0 = t * 64;
        __syncthreads();
#pragma unroll
        for (int r = 0; r < 4; ++r) {
            int e = tid + r * 256;          // 0..1023 float4 units
            int c = e >> 4, nq = e & 15;
            float4 v = *(const float4*)(xb + c * N_ + nb0 + nq * 4);
            pt[(nq * 4 + 0) * 68 + c] = v.x;
            pt[(nq * 4 + 1) * 68 + c] = v.y;
            pt[(nq * 4 + 2) * 68 + c] = v.z;
            pt[(nq * 4 + 3) * 68 + c] = v.w;
        }
        if (tid < 64) spn[tid] = pnorm_ws[b * N_ + nb0 + tid];
        __syncthreads();
#pragma unroll
        for (int pp = 0; pp < 8; ++pp) {
            int nl = sub * 8 + pp;
            const float4* pv = (const float4*)(pt + nl * 68);
            float a0 = 0.f, a1 = 0.f, a2 = 0.f, a3 = 0.f;
#pragma unroll
            for (int c4 = 0; c4 < 16; ++c4) {
                float4 p = pv[c4];
                a0 = fmaf(qv[c4].x, p.x, a0);
                a1 = fmaf(qv[c4].y, p.y, a1);
                a2 = fmaf(qv[c4].z, p.z, a2);
                a3 = fmaf(qv[c4].w, p.w, a3);
            }
            float dot = (a0 + a1) + (a2 + a3);
            float d = qn + spn[nl] - 2.0f * dot;
            u32 db = __float_as_uint(d);
            db = (db & 0x80000000u) ? ~db : (db | 0x80000000u);  // monotone (handles d<0)
            u64 key = ((u64)db << 32) | (u32)(nb0 + nl);
            if (key < worst) {
                int j = 16;
                while (j > 0 && L[j - 1] > key) { L[j] = L[j - 1]; --j; }
                L[j] = key;
                worst = L[16];
            }
        }
    }
    __syncthreads();
    if (tid < 32) {
        int pos[8];
#pragma unroll
        for (int s2 = 0; s2 < 8; ++s2) pos[s2] = 0;
        u16* outp = nbr_ws + (b * M_ + m0 + tid) * KNB;
        for (int r = 0; r < 17; ++r) {
            u64 best = ~0ULL; int bs = 0;
#pragma unroll
            for (int s2 = 0; s2 < 8; ++s2) {
                u64 k2 = (pos[s2] < 17) ? lists[(tid + 32 * s2) * 17 + pos[s2]] : ~0ULL;
                if (k2 < best) { best = k2; bs = s2; }
            }
#pragma unroll
            for (int s2 = 0; s2 < 8; ++s2) pos[s2] += (s2 == bs) ? 1 : 0;
            if (r > 0) outp[r - 1] = (u16)clampN((int)(best & 0xFFFFFFFFu));
        }
    }
}

// =================== fused edge-conv x3 + k-maxpool ===================
__device__ __forceinline__ void mm_tile(float a[4][4], const float* __restrict__ w,
                                        const float* __restrict__ s, int ni) {
#pragma unroll 8
    for (int i = 0; i < ni; ++i) {
        const float4 w4 = *(const float4*)(w + i * 64);
        const float4 e4 = *(const float4*)(s + i * 64);
        a[0][0] = fmaf(w4.x, e4.x, a[0][0]);
        a[0][1] = fmaf(w4.x, e4.y, a[0][1]);
        a[0][2] = fmaf(w4.x, e4.z, a[0][2]);
        a[0][3] = fmaf(w4.x, e4.w, a[0][3]);
        a[1][0] = fmaf(w4.y, e4.x, a[1][0]);
        a[1][1] = fmaf(w4.y, e4.y, a[1][1]);
        a[1][2] = fmaf(w4.y, e4.z, a[1][2]);
        a[1][3] = fmaf(w4.y, e4.w, a[1][3]);
        a[2][0] = fmaf(w4.z, e4.x, a[2][0]);
        a[2][1] = fmaf(w4.z, e4.y, a[2][1]);
        a[2][2] = fmaf(w4.z, e4.z, a[2][2]);
        a[2][3] = fmaf(w4.z, e4.w, a[2][3]);
        a[3][0] = fmaf(w4.w, e4.x, a[3][0]);
        a[3][1] = fmaf(w4.w, e4.y, a[3][1]);
        a[3][2] = fmaf(w4.w, e4.z, a[3][2]);
        a[3][3] = fmaf(w4.w, e4.w, a[3][3]);
    }
}

__global__ __launch_bounds__(256) void conv_kernel(const float* __restrict__ x,
                                                   const u16* __restrict__ idx_ws,
                                                   const u16* __restrict__ nbr_ws,
                                                   const float* __restrict__ wt,
                                                   const float* __restrict__ bias0,
                                                   const float* __restrict__ bias1,
                                                   const float* __restrict__ bias2,
                                                   float* __restrict__ out0) {
    __shared__ float E[128 * 64];    // rows 0..63 center, 64..127 nd (later h2)
    __shared__ float H0[64 * 64];
    __shared__ float H1[64 * 64];

    const int tid = threadIdx.x;
    const int b = blockIdx.x >> 9;
    const int m0 = (blockIdx.x & 511) * 4;    // 4 queries x 16 neighbors = 64 cols
    const float* xb = x + b * C_ * N_;

    {   // stage edge tile
        const int col = tid & 63;
        const int half = tid >> 6;           // 0..3 -> 16 channels each
        const int m = m0 + (col >> 4);
        const int k = col & 15;
        const int selfm = clampN((int)idx_ws[b * M_ + m]);
        const int nbr = clampN((int)nbr_ws[(b * M_ + m) * KNB + k]);
#pragma unroll
        for (int c2 = 0; c2 < 16; ++c2) {
            int c = half * 16 + c2;
            float ctr = xb[c * N_ + selfm];
            float nb = xb[c * N_ + nbr];
            E[c * 64 + col] = ctr;
            E[(64 + c) * 64 + col] = __fsub_rn(nb, ctr);
        }
    }
    __syncthreads();

    const int o0 = (tid >> 4) * 4;
    const int c0 = (tid & 15) * 4;
    float a[4][4];

    {   // conv0: in = [center, nd] (E rows 0..127)
        float4 bb = *(const float4*)(bias0 + o0);
        a[0][0] = a[0][1] = a[0][2] = a[0][3] = bb.x;
        a[1][0] = a[1][1] = a[1][2] = a[1][3] = bb.y;
        a[2][0] = a[2][1] = a[2][2] = a[2][3] = bb.z;
        a[3][0] = a[3][1] = a[3][2] = a[3][3] = bb.w;
        mm_tile(a, wt + o0, E + c0, 128);
#pragma unroll
        for (int oo = 0; oo < 4; ++oo) {
            float4 v = make_float4(fmaxf(a[oo][0], 0.f), fmaxf(a[oo][1], 0.f),
                                   fmaxf(a[oo][2], 0.f), fmaxf(a[oo][3], 0.f));
            *(float4*)(H0 + (o0 + oo) * 64 + c0) = v;
        }
    }
    __syncthreads();

    {   // conv1: in = [h0 (H0), center (E rows 0..63)]
        float4 bb = *(const float4*)(bias1 + o0);
        a[0][0] = a[0][1] = a[0][2] = a[0][3] = bb.x;
        a[1][0] = a[1][1] = a[1][2] = a[1][3] = bb.y;
        a[2][0] = a[2][1] = a[2][2] = a[2][3] = bb.z;
        a[3][0] = a[3][1] = a[3][2] = a[3][3] = bb.w;
        mm_tile(a, wt + 8192 + o0, H0 + c0, 64);
        mm_tile(a, wt + 8192 + 64 * 64 + o0, E + c0, 64);
#pragma unroll
        for (int oo = 0; oo < 4; ++oo) {
            float4 v = make_float4(fmaxf(a[oo][0], 0.f), fmaxf(a[oo][1], 0.f),
                                   fmaxf(a[oo][2], 0.f), fmaxf(a[oo][3], 0.f));
            *(float4*)(H1 + (o0 + oo) * 64 + c0) = v;
        }
    }
    __syncthreads();

    {   // conv2: in = [h1 (H1), h0 (H0), center (E rows 0..63)]; no relu
        float4 bb = *(const float4*)(bias2 + o0);
        a[0][0] = a[0][1] = a[0][2] = a[0][3] = bb.x;
        a[1][0] = a[1][1] = a[1][2] = a[1][3] = bb.y;
        a[2][0] = a[2][1] = a[2][2] = a[2][3] = bb.z;
        a[3][0] = a[3][1] = a[3][2] = a[3][3] = bb.w;
        mm_tile(a, wt + 16384 + o0, H1 + c0, 64);
        mm_tile(a, wt + 16384 + 64 * 64 + o0, H0 + c0, 64);
        mm_tile(a, wt + 16384 + 128 * 64 + o0, E + c0, 64);
#pragma unroll
        for (int oo = 0; oo < 4; ++oo) {   // h2 overwrites dead nd rows
            float4 v = make_float4(a[oo][0], a[oo][1], a[oo][2], a[oo][3]);
            *(float4*)(E + (64 + o0 + oo) * 64 + c0) = v;
        }
    }
    __syncthreads();

    // max over k; out channels = [h2, h1, h0, center]
#pragma unroll
    for (int r = 0; r < 4; ++r) {
        int e = tid + r * 256;              // 0..1023 = 256 ch x 4 m
        int ch = e >> 2, mloc = e & 3;
        int colb = mloc * 16;
        float v;
        if (ch < 64) {
            const float* row = E + (64 + ch) * 64 + colb;
            v = row[0];
#pragma unroll
            for (int k = 1; k < 16; ++k) v = fmaxf(v, row[k]);
        } else if (ch < 128) {
            const float* row = H1 + (ch - 64) * 64 + colb;
            v = row[0];
#pragma unroll
            for (int k = 1; k < 16; ++k) v = fmaxf(v, row[k]);
        } else if (ch < 192) {
            const float* row = H0 + (ch - 128) * 64 + colb;
            v = row[0];
#pragma unroll
            for (int k = 1; k < 16; ++k) v = fmaxf(v, row[k]);
        } else {
            v = E[(ch - 192) * 64 + colb];   // center, identical across k
        }
        out0[((b * 256 + ch) << 11) + m0 + mloc] = v;
    }
}

extern "C" void kernel_launch(void* const* d_in, const int* in_sizes, int n_in,
                              void* d_out, int out_size, void* d_ws, size_t ws_size,
                              hipStream_t stream) {
    const float* x   = (const float*)d_in[0];
    const float* xyz = (const float*)d_in[1];
    const float* W0  = (const float*)d_in[2];
    const float* b0  = (const float*)d_in[3];
    const float* W1  = (const float*)d_in[4];
    const float* b1  = (const float*)d_in[5];
    const float* W2  = (const float*)d_in[6];
    const float* b2  = (const float*)d_in[7];

    float* out  = (float*)d_out;                 // FLOAT32 output buffer
    float* out0 = out;                           // y: 4*256*2048
    float* out1 = out + 4 * 256 * 2048;          // sampled_xyz: 4*3*2048
    float* out2 = out1 + 4 * 3 * 2048;           // sampled_idx (f32): 4*2048

    char* ws = (char*)d_ws;
    u16*   idx_ws   = (u16*)ws;                  // 16384 B
    u16*   nbr_ws   = (u16*)(ws + 16384);        // 262144 B
    float* pnorm_ws = (float*)(ws + 278528);     // 131072 B
    float* wt_ws    = (float*)(ws + 409600);     // 114688 B

    fps_kernel<<<4, 512, 0, stream>>>(xyz, idx_ws);
    gather_kernel<<<32, 256, 0, stream>>>(xyz, idx_ws, out1, out2);
    pnorm_kernel<<<128, 256, 0, stream>>>(x, pnorm_ws);
    wtrans_kernel<<<112, 256, 0, stream>>>(W0, W1, W2, wt_ws);
    knn_kernel<<<256, 256, 0, stream>>>(x, idx_ws, pnorm_ws, nbr_ws);
    conv_kernel<<<2048, 256, 0, stream>>>(x, idx_ws, nbr_ws, wt_ws, b0, b1, b2, out0);
}

// Round 12
// 3006.237 us; speedup vs baseline: 1.1052x; 1.1052x over previous
//
#include <hip/hip_runtime.h>
#include <hip/hip_bf16.h>
#include <stdint.h>

typedef unsigned long long u64;
typedef unsigned int u32;
typedef unsigned short u16;

#define B_   4
#define C_   64
#define N_   8192
#define M_   2048
#define KNB  16
#define FLT_MAX_ 3.402823466e+38f

__device__ __forceinline__ int clampN(int v) {
    return v < 0 ? 0 : (v > N_ - 1 ? N_ - 1 : v);
}

// ---------------- ws layout (bytes) — TOTAL 524288 ----------------
// idx_ws   : u16[B_*M_]       @ 0       (16384 B)
// nbr_ws   : u16[B_*M_*KNB]   @ 16384   (262144 B)
// pnorm_ws : float[B_*N_]     @ 278528  (131072 B)
// wt_ws    : float[448*64]    @ 409600  (114688 B)
// d_out is FLOAT32 (round-6 discovery): all output stores are f32.

__device__ __forceinline__ void pin4(float4& v) {
    asm volatile("" : "+v"(v.x), "+v"(v.y), "+v"(v.z), "+v"(v.w));
}

// DPP wave64 max -> returns wave max broadcast (via lane 63 readlane).
__device__ __forceinline__ float wave_fmax_dpp(float v) {
    float t;
    t = __int_as_float(__builtin_amdgcn_update_dpp(0, __float_as_int(v), 0x111, 0xf, 0xf, true)); v = fmaxf(v, t);
    t = __int_as_float(__builtin_amdgcn_update_dpp(0, __float_as_int(v), 0x112, 0xf, 0xf, true)); v = fmaxf(v, t);
    t = __int_as_float(__builtin_amdgcn_update_dpp(0, __float_as_int(v), 0x114, 0xf, 0xf, true)); v = fmaxf(v, t);
    t = __int_as_float(__builtin_amdgcn_update_dpp(0, __float_as_int(v), 0x118, 0xf, 0xf, true)); v = fmaxf(v, t);
    t = __int_as_float(__builtin_amdgcn_update_dpp(0, __float_as_int(v), 0x142, 0xa, 0xf, true)); v = fmaxf(v, t);
    t = __int_as_float(__builtin_amdgcn_update_dpp(0, __float_as_int(v), 0x143, 0xc, 0xf, true)); v = fmaxf(v, t);
    return __int_as_float(__builtin_amdgcn_readlane(__float_as_int(v), 63));
}

// ======================= FPS =======================
// np-exact per-iteration math; see r7-r11 notes. ROUND 12 (experiment):
// five different fps bodies all time 2.25-2.55ms regardless of instruction
// count -> not issue-bound. Hypothesis: 4-block dispatch (1.5% util) never
// triggers DPM clock boost (~1.1GHz effective; cycle model matches at that
// clock). Test: 64 blocks = 16 identical replicas per batch (benign race,
// identical u16 writes). Critical path unchanged; only utilization rises.
#define FPS_STEP(PX, PY, PZ, DD, J)                                          \
    {                                                                        \
        float dx = __fsub_rn((PX), lx);                                      \
        float dy = __fsub_rn((PY), ly);                                      \
        float dz = __fsub_rn((PZ), lz);                                      \
        float d = __fadd_rn(__fadd_rn(__fmul_rn(dx, dx), __fmul_rn(dy, dy)), \
                            __fmul_rn(dz, dz));                              \
        float nd = fminf((DD), d);                                           \
        (DD) = nd;                                                           \
        bool gt = nd > fm;                                                   \
        fm = gt ? nd : fm;                                                   \
        fj = gt ? (J) : fj;                                                  \
        fx = gt ? (PX) : fx;                                                 \
        fy = gt ? (PY) : fy;                                                 \
        fz = gt ? (PZ) : fz;                                                 \
    }

__global__ __launch_bounds__(512, 2) void fps_kernel(const float* __restrict__ xyz,
                                                     u16* __restrict__ idx_ws) {
    const int b = blockIdx.x & 3;           // 16 replicas per batch (DPM test)
    const int tid = threadIdx.x;
    const int lane = tid & 63;
    const int w = tid >> 6;                 // 8 waves
    const float* xb = xyz + b * 3 * N_;
    const int n0 = tid * 16;

    float4 px[4], py[4], pz[4], dd[4];
#pragma unroll
    for (int j4 = 0; j4 < 4; ++j4) {
        px[j4] = *(const float4*)(xb + n0 + j4 * 4);
        py[j4] = *(const float4*)(xb + N_ + n0 + j4 * 4);
        pz[j4] = *(const float4*)(xb + 2 * N_ + n0 + j4 * 4);
        pin4(px[j4]); pin4(py[j4]); pin4(pz[j4]);
        dd[j4] = make_float4(FLT_MAX_, FLT_MAX_, FLT_MAX_, FLT_MAX_);
    }

    __shared__ float4 red4[2][8];   // {wavemax, x, y, z}
    __shared__ int    redi[2][8];

    int cur = 0;
    float lx = xb[0], ly = xb[N_], lz = xb[2 * N_];
    if (tid == 0) idx_ws[b * M_ + 0] = 0;

    for (int s = 1; s < M_; ++s) {
        float fm = -1.0f, fx = 0.f, fy = 0.f, fz = 0.f;
        int fj = 0;
#pragma unroll
        for (int j4 = 0; j4 < 4; ++j4) {
            FPS_STEP(px[j4].x, py[j4].x, pz[j4].x, dd[j4].x, j4 * 4 + 0);
            FPS_STEP(px[j4].y, py[j4].y, pz[j4].y, dd[j4].y, j4 * 4 + 1);
            FPS_STEP(px[j4].z, py[j4].z, pz[j4].z, dd[j4].z, j4 * 4 + 2);
            FPS_STEP(px[j4].w, py[j4].w, pz[j4].w, dd[j4].w, j4 * 4 + 3);
        }
        float wm = wave_fmax_dpp(fm);       // wave-uniform
        u64 bal = __ballot(fm == wm);       // >=1 bit set
        int winlane = (int)__ffsll(bal) - 1;
        const int par = s & 1;
        if (lane == winlane) {
            red4[par][w] = make_float4(wm, fx, fy, fz);
            redi[par][w] = n0 + fj;
        }
        __syncthreads();
        float4 p0 = red4[par][0];
        float g = p0.x; float nlx = p0.y, nly = p0.z, nlz = p0.w;
        int ncur = redi[par][0];
#pragma unroll
        for (int ww = 1; ww < 8; ++ww) {
            float4 p = red4[par][ww];
            int id = redi[par][ww];
            bool gt = p.x > g;              // strict: keeps first wave on ties
            g = gt ? p.x : g;
            nlx = gt ? p.y : nlx; nly = gt ? p.z : nly; nlz = gt ? p.w : nlz;
            ncur = gt ? id : ncur;
        }
        lx = nlx; ly = nly; lz = nlz; cur = ncur;
        if (tid == 0) idx_ws[b * M_ + s] = (u16)cur;
        // single barrier per iter: next iter writes red4[par^1]
    }
}

// =================== gather: out1 (xyz) / out2 (idx), f32 ===================
__global__ __launch_bounds__(256) void gather_kernel(const float* __restrict__ xyz,
                                                     const u16* __restrict__ idx_ws,
                                                     float* __restrict__ out1,
                                                     float* __restrict__ out2) {
    int gid = blockIdx.x * 256 + threadIdx.x;   // 8192
    int b = gid >> 11, m = gid & 2047;
    int idx = clampN((int)idx_ws[b * M_ + m]);
    out2[b * M_ + m] = (float)idx;
    const float* xyzb = xyz + b * 3 * N_;
#pragma unroll
    for (int d = 0; d < 3; ++d)
        out1[(b * 3 + d) * M_ + m] = xyzb[d * N_ + idx];
}

// =================== point squared norms ===================
__global__ __launch_bounds__(256) void pnorm_kernel(const float* __restrict__ x,
                                                    float* __restrict__ pnorm_ws) {
    int gid = blockIdx.x * 256 + threadIdx.x;   // 32768
    int b = gid >> 13, n = gid & 8191;
    const float* xb = x + b * C_ * N_ + n;
    float acc = 0.f;
#pragma unroll 16
    for (int c = 0; c < C_; ++c) { float v = xb[c * N_]; acc = fmaf(v, v, acc); }
    pnorm_ws[gid] = acc;
}

// =================== weight transpose: W[o][i] -> Wt[i][o] ===================
__global__ __launch_bounds__(256) void wtrans_kernel(const float* __restrict__ W0,
                                                     const float* __restrict__ W1,
                                                     const float* __restrict__ W2,
                                                     float* __restrict__ wt) {
    int e = blockIdx.x * 256 + threadIdx.x;     // 28672
    if (e < 8192) {
        int i = e >> 6, o = e & 63;
        wt[e] = W0[o * 128 + i];
    } else if (e < 16384) {
        int e2 = e - 8192; int i = e2 >> 6, o = e2 & 63;
        wt[8192 + e2] = W1[o * 128 + i];
    } else {
        int e2 = e - 16384; int i = e2 >> 6, o = e2 & 63;
        wt[16384 + e2] = W2[o * 192 + i];
    }
}

// =================== KNN top-17 tiled (drop rank-0 self) ===================
__global__ __launch_bounds__(256) void knn_kernel(const float* __restrict__ x,
                                                  const u16* __restrict__ idx_ws,
                                                  const float* __restrict__ pnorm_ws,
                                                  u16* __restrict__ nbr_ws) {
    __shared__ float pt[64 * 68];
    __shared__ float spn[64];
    __shared__ u64 lists[256 * 17];

    const int tid = threadIdx.x;
    const int b = blockIdx.x >> 6;
    const int m0 = (blockIdx.x & 63) * 32;
    const int q = tid & 31, sub = tid >> 5;
    const int m = m0 + q;
    const float* xb = x + b * C_ * N_;
    const int self = clampN((int)idx_ws[b * M_ + m]);

    float4 qv[16];
#pragma unroll
    for (int c4 = 0; c4 < 16; ++c4) {
        qv[c4].x = xb[(c4 * 4 + 0) * N_ + self];
        qv[c4].y = xb[(c4 * 4 + 1) * N_ + self];
        qv[c4].z = xb[(c4 * 4 + 2) * N_ + self];
        qv[c4].w = xb[(c4 * 4 + 3) * N_ + self];
    }
    const float qn = pnorm_ws[b * N_ + self];

    u64* L = lists + tid * 17;
#pragma unroll
    for (int j = 0; j < 17; ++j) L[j] = ~0ULL;
    u64 worst = ~0ULL;

    for (int t = 0; t < N_ / 64; ++t) {
        const int nb0 = t * 64;
        __syncthreads();
#pragma unroll
        for (int r = 0; r < 4; ++r) {
            int e = tid + r * 256;          // 0..1023 float4 units
            int c = e >> 4, nq = e & 15;
            float4 v = *(const float4*)(xb + c * N_ + nb0 + nq * 4);
            pt[(nq * 4 + 0) * 68 + c] = v.x;
            pt[(nq * 4 + 1) * 68 + c] = v.y;
            pt[(nq * 4 + 2) * 68 + c] = v.z;
            pt[(nq * 4 + 3) * 68 + c] = v.w;
        }
        if (tid < 64) spn[tid] = pnorm_ws[b * N_ + nb0 + tid];
        __syncthreads();
#pragma unroll
        for (int pp = 0; pp < 8; ++pp) {
            int nl = sub * 8 + pp;
            const float4* pv = (const float4*)(pt + nl * 68);
            float a0 = 0.f, a1 = 0.f, a2 = 0.f, a3 = 0.f;
#pragma unroll
            for (int c4 = 0; c4 < 16; ++c4) {
                float4 p = pv[c4];
                a0 = fmaf(qv[c4].x, p.x, a0);
                a1 = fmaf(qv[c4].y, p.y, a1);
                a2 = fmaf(qv[c4].z, p.z, a2);
                a3 = fmaf(qv[c4].w, p.w, a3);
            }
            float dot = (a0 + a1) + (a2 + a3);
            float d = qn + spn[nl] - 2.0f * dot;
            u32 db = __float_as_uint(d);
            db = (db & 0x80000000u) ? ~db : (db | 0x80000000u);  // monotone (handles d<0)
            u64 key = ((u64)db << 32) | (u32)(nb0 + nl);
            if (key < worst) {
                int j = 16;
                while (j > 0 && L[j - 1] > key) { L[j] = L[j - 1]; --j; }
                L[j] = key;
                worst = L[16];
            }
        }
    }
    __syncthreads();
    if (tid < 32) {
        int pos[8];
#pragma unroll
        for (int s2 = 0; s2 < 8; ++s2) pos[s2] = 0;
        u16* outp = nbr_ws + (b * M_ + m0 + tid) * KNB;
        for (int r = 0; r < 17; ++r) {
            u64 best = ~0ULL; int bs = 0;
#pragma unroll
            for (int s2 = 0; s2 < 8; ++s2) {
                u64 k2 = (pos[s2] < 17) ? lists[(tid + 32 * s2) * 17 + pos[s2]] : ~0ULL;
                if (k2 < best) { best = k2; bs = s2; }
            }
#pragma unroll
            for (int s2 = 0; s2 < 8; ++s2) pos[s2] += (s2 == bs) ? 1 : 0;
            if (r > 0) outp[r - 1] = (u16)clampN((int)(best & 0xFFFFFFFFu));
        }
    }
}

// =================== fused edge-conv x3 + k-maxpool ===================
__device__ __forceinline__ void mm_tile(float a[4][4], const float* __restrict__ w,
                                        const float* __restrict__ s, int ni) {
#pragma unroll 8
    for (int i = 0; i < ni; ++i) {
        const float4 w4 = *(const float4*)(w + i * 64);
        const float4 e4 = *(const float4*)(s + i * 64);
        a[0][0] = fmaf(w4.x, e4.x, a[0][0]);
        a[0][1] = fmaf(w4.x, e4.y, a[0][1]);
        a[0][2] = fmaf(w4.x, e4.z, a[0][2]);
        a[0][3] = fmaf(w4.x, e4.w, a[0][3]);
        a[1][0] = fmaf(w4.y, e4.x, a[1][0]);
        a[1][1] = fmaf(w4.y, e4.y, a[1][1]);
        a[1][2] = fmaf(w4.y, e4.z, a[1][2]);
        a[1][3] = fmaf(w4.y, e4.w, a[1][3]);
        a[2][0] = fmaf(w4.z, e4.x, a[2][0]);
        a[2][1] = fmaf(w4.z, e4.y, a[2][1]);
        a[2][2] = fmaf(w4.z, e4.z, a[2][2]);
        a[2][3] = fmaf(w4.z, e4.w, a[2][3]);
        a[3][0] = fmaf(w4.w, e4.x, a[3][0]);
        a[3][1] = fmaf(w4.w, e4.y, a[3][1]);
        a[3][2] = fmaf(w4.w, e4.z, a[3][2]);
        a[3][3] = fmaf(w4.w, e4.w, a[3][3]);
    }
}

__global__ __launch_bounds__(256) void conv_kernel(const float* __restrict__ x,
                                                   const u16* __restrict__ idx_ws,
                                                   const u16* __restrict__ nbr_ws,
                                                   const float* __restrict__ wt,
                                                   const float* __restrict__ bias0,
                                                   const float* __restrict__ bias1,
                                                   const float* __restrict__ bias2,
                                                   float* __restrict__ out0) {
    __shared__ float E[128 * 64];    // rows 0..63 center, 64..127 nd (later h2)
    __shared__ float H0[64 * 64];
    __shared__ float H1[64 * 64];

    const int tid = threadIdx.x;
    const int b = blockIdx.x >> 9;
    const int m0 = (blockIdx.x & 511) * 4;    // 4 queries x 16 neighbors = 64 cols
    const float* xb = x + b * C_ * N_;

    {   // stage edge tile
        const int col = tid & 63;
        const int half = tid >> 6;           // 0..3 -> 16 channels each
        const int m = m0 + (col >> 4);
        const int k = col & 15;
        const int selfm = clampN((int)idx_ws[b * M_ + m]);
        const int nbr = clampN((int)nbr_ws[(b * M_ + m) * KNB + k]);
#pragma unroll
        for (int c2 = 0; c2 < 16; ++c2) {
            int c = half * 16 + c2;
            float ctr = xb[c * N_ + selfm];
            float nb = xb[c * N_ + nbr];
            E[c * 64 + col] = ctr;
            E[(64 + c) * 64 + col] = __fsub_rn(nb, ctr);
        }
    }
    __syncthreads();

    const int o0 = (tid >> 4) * 4;
    const int c0 = (tid & 15) * 4;
    float a[4][4];

    {   // conv0: in = [center, nd] (E rows 0..127)
        float4 bb = *(const float4*)(bias0 + o0);
        a[0][0] = a[0][1] = a[0][2] = a[0][3] = bb.x;
        a[1][0] = a[1][1] = a[1][2] = a[1][3] = bb.y;
        a[2][0] = a[2][1] = a[2][2] = a[2][3] = bb.z;
        a[3][0] = a[3][1] = a[3][2] = a[3][3] = bb.w;
        mm_tile(a, wt + o0, E + c0, 128);
#pragma unroll
        for (int oo = 0; oo < 4; ++oo) {
            float4 v = make_float4(fmaxf(a[oo][0], 0.f), fmaxf(a[oo][1], 0.f),
                                   fmaxf(a[oo][2], 0.f), fmaxf(a[oo][3], 0.f));
            *(float4*)(H0 + (o0 + oo) * 64 + c0) = v;
        }
    }
    __syncthreads();

    {   // conv1: in = [h0 (H0), center (E rows 0..63)]
        float4 bb = *(const float4*)(bias1 + o0);
        a[0][0] = a[0][1] = a[0][2] = a[0][3] = bb.x;
        a[1][0] = a[1][1] = a[1][2] = a[1][3] = bb.y;
        a[2][0] = a[2][1] = a[2][2] = a[2][3] = bb.z;
        a[3][0] = a[3][1] = a[3][2] = a[3][3] = bb.w;
        mm_tile(a, wt + 8192 + o0, H0 + c0, 64);
        mm_tile(a, wt + 8192 + 64 * 64 + o0, E + c0, 64);
#pragma unroll
        for (int oo = 0; oo < 4; ++oo) {
            float4 v = make_float4(fmaxf(a[oo][0], 0.f), fmaxf(a[oo][1], 0.f),
                                   fmaxf(a[oo][2], 0.f), fmaxf(a[oo][3], 0.f));
            *(float4*)(H1 + (o0 + oo) * 64 + c0) = v;
        }
    }
    __syncthreads();

    {   // conv2: in = [h1 (H1), h0 (H0), center (E rows 0..63)]; no relu
        float4 bb = *(const float4*)(bias2 + o0);
        a[0][0] = a[0][1] = a[0][2] = a[0][3] = bb.x;
        a[1][0] = a[1][1] = a[1][2] = a[1][3] = bb.y;
        a[2][0] = a[2][1] = a[2][2] = a[2][3] = bb.z;
        a[3][0] = a[3][1] = a[3][2] = a[3][3] = bb.w;
        mm_tile(a, wt + 16384 + o0, H1 + c0, 64);
        mm_tile(a, wt + 16384 + 64 * 64 + o0, H0 + c0, 64);
        mm_tile(a, wt + 16384 + 128 * 64 + o0, E + c0, 64);
#pragma unroll
        for (int oo = 0; oo < 4; ++oo) {   // h2 overwrites dead nd rows
            float4 v = make_float4(a[oo][0], a[oo][1], a[oo][2], a[oo][3]);
            *(float4*)(E + (64 + o0 + oo) * 64 + c0) = v;
        }
    }
    __syncthreads();

    // max over k; out channels = [h2, h1, h0, center]
#pragma unroll
    for (int r = 0; r < 4; ++r) {
        int e = tid + r * 256;              // 0..1023 = 256 ch x 4 m
        int ch = e >> 2, mloc = e & 3;
        int colb = mloc * 16;
        float v;
        if (ch < 64) {
            const float* row = E + (64 + ch) * 64 + colb;
            v = row[0];
#pragma unroll
            for (int k = 1; k < 16; ++k) v = fmaxf(v, row[k]);
        } else if (ch < 128) {
            const float* row = H1 + (ch - 64) * 64 + colb;
            v = row[0];
#pragma unroll
            for (int k = 1; k < 16; ++k) v = fmaxf(v, row[k]);
        } else if (ch < 192) {
            const float* row = H0 + (ch - 128) * 64 + colb;
            v = row[0];
#pragma unroll
            for (int k = 1; k < 16; ++k) v = fmaxf(v, row[k]);
        } else {
            v = E[(ch - 192) * 64 + colb];   // center, identical across k
        }
        out0[((b * 256 + ch) << 11) + m0 + mloc] = v;
    }
}

extern "C" void kernel_launch(void* const* d_in, const int* in_sizes, int n_in,
                              void* d_out, int out_size, void* d_ws, size_t ws_size,
                              hipStream_t stream) {
    const float* x   = (const float*)d_in[0];
    const float* xyz = (const float*)d_in[1];
    const float* W0  = (const float*)d_in[2];
    const float* b0  = (const float*)d_in[3];
    const float* W1  = (const float*)d_in[4];
    const float* b1  = (const float*)d_in[5];
    const float* W2  = (const float*)d_in[6];
    const float* b2  = (const float*)d_in[7];

    float* out  = (float*)d_out;                 // FLOAT32 output buffer
    float* out0 = out;                           // y: 4*256*2048
    float* out1 = out + 4 * 256 * 2048;          // sampled_xyz: 4*3*2048
    float* out2 = out1 + 4 * 3 * 2048;           // sampled_idx (f32): 4*2048

    char* ws = (char*)d_ws;
    u16*   idx_ws   = (u16*)ws;                  // 16384 B
    u16*   nbr_ws   = (u16*)(ws + 16384);        // 262144 B
    float* pnorm_ws = (float*)(ws + 278528);     // 131072 B
    float* wt_ws    = (float*)(ws + 409600);     // 114688 B

    // independent prep first (warms chip before the long serial fps)
    pnorm_kernel<<<128, 256, 0, stream>>>(x, pnorm_ws);
    wtrans_kernel<<<112, 256, 0, stream>>>(W0, W1, W2, wt_ws);
    fps_kernel<<<64, 512, 0, stream>>>(xyz, idx_ws);   // 16 replicas/batch (DPM test)
    gather_kernel<<<32, 256, 0, stream>>>(xyz, idx_ws, out1, out2);
    knn_kernel<<<256, 256, 0, stream>>>(x, idx_ws, pnorm_ws, nbr_ws);
    conv_kernel<<<2048, 256, 0, stream>>>(x, idx_ws, nbr_ws, wt_ws, b0, b1, b2, out0);
}